// Round 1
// baseline (296.571 us; speedup 1.0000x reference)
//
#include <hip/hip_runtime.h>

// DeformConv2d: B=16, Cin=64, Cout=64, H=W=64, K=3, stride=1, pad=1, dil=1
// d_in: x[16,64,64,64], w_off[18,64,3,3], b_off[18], w_dcn[64,64,3,3], b_dcn[64]
// d_out: [16,64,64,64] fp32

#define KOFF 18          // 2*K*K offset channels
#define CIN 64
#define COUT 64
#define HDIM 64
#define WDIM 64
#define CCHUNK 8         // cin per main-loop chunk
#define KCH (CCHUNK * 9) // 72 k-values per chunk

// ---------------------------------------------------------------------------
// Kernel C: transpose w_dcn [co][cin*9] -> w_t [cin*9][co] for coalesced LDS
// staging in the main kernel.
__global__ void transpose_w(const float* __restrict__ w_dcn,
                            float* __restrict__ w_t) {
    int e = blockIdx.x * 256 + threadIdx.x;   // 576*64 = 36864 total
    if (e < 576 * 64) {
        int co = e & 63;
        int k  = e >> 6;
        w_t[e] = w_dcn[co * 576 + k];
    }
}

// ---------------------------------------------------------------------------
// Main fused kernel: one block per (b, ho) row of 64 output pixels.
//  phase -1: offset conv for this row (18 ch x 64 px), fused (no ws traffic)
//  phase  0: bilinear geometry per (tap, px) into LDS
//  main loop over cin chunks: gather cols -> LDS, stage weights -> LDS,
//                             4x4-register-tile fp32 GEMM (64 co x 64 px)
__launch_bounds__(256)
__global__ void dcn_main(const float* __restrict__ x,
                         const float* __restrict__ w_off,
                         const float* __restrict__ b_off,
                         const float* __restrict__ w_dcn,
                         const float* __restrict__ w_t,
                         const float* __restrict__ b_dcn,
                         float* __restrict__ out,
                         int use_wt) {
    const int bx = blockIdx.x;       // 0..1023
    const int b  = bx >> 6;          // batch
    const int ho = bx & 63;          // output row
    const int t  = threadIdx.x;      // 0..255
    const int p  = t & 63;           // pixel (wo) for cooperative phases
    const int g  = t >> 6;           // wave id 0..3

    __shared__ float offlds[KOFF * 64];            // 4.6 KB
    __shared__ int   gy0[9 * 64];                  // geometry: 9.2 KB total
    __shared__ int   gx0[9 * 64];
    __shared__ float gwy[9 * 64];
    __shared__ float gwx[9 * 64];
    __shared__ float smem_big[2 * KCH * 64];       // 36.9 KB (wlds | cols)

    const float* xb = x + (size_t)b * CIN * HDIM * WDIM;

    // ---------------- phase -1: offset conv (18 channels, this row) --------
    {
        // 4 cin-chunks of 16 (one per wave), 18 accumulators per thread.
        const int cinbase = __builtin_amdgcn_readfirstlane(g * 16);
        const float* wbase = w_off + cinbase * 9;  // w_off[co*576 + cin*9 + ky*3 + kx]
        float acc[KOFF];
#pragma unroll
        for (int i = 0; i < KOFF; ++i) acc[i] = 0.f;

        for (int ci = 0; ci < 16; ++ci) {
            const float* xc = xb + (size_t)(cinbase + ci) * (HDIM * WDIM);
#pragma unroll
            for (int ky = 0; ky < 3; ++ky) {
                int y = ho + ky - 1;
                bool yok = ((unsigned)y < (unsigned)HDIM);
#pragma unroll
                for (int kx = 0; kx < 3; ++kx) {
                    int xcol = p + kx - 1;
                    bool ok = yok && ((unsigned)xcol < (unsigned)WDIM);
                    float xv = ok ? xc[y * WDIM + xcol] : 0.f;
#pragma unroll
                    for (int co = 0; co < KOFF; ++co)
                        acc[co] += xv * wbase[co * 576 + ci * 9 + ky * 3 + kx];
                }
            }
        }
        // partial sums -> LDS (alias smem_big), reduce 4 chunks
        float* partial = smem_big;                 // 4*18*64 = 4608 floats
#pragma unroll
        for (int co = 0; co < KOFF; ++co)
            partial[(g * KOFF + co) * 64 + p] = acc[co];
        __syncthreads();
        for (int e = t; e < KOFF * 64; e += 256) {
            int co = e >> 6, pp = e & 63;
            float s = b_off[co];
#pragma unroll
            for (int q = 0; q < 4; ++q) s += partial[(q * KOFF + co) * 64 + pp];
            offlds[e] = s;
        }
        __syncthreads();
    }

    // ---------------- phase 0: bilinear geometry ---------------------------
    for (int e = t; e < 9 * 64; e += 256) {
        int kk = e >> 6, pp = e & 63;
        float py = offlds[(2 * kk) * 64 + pp] + (float)(kk / 3) + (float)(ho - 1);
        float px = offlds[(2 * kk + 1) * 64 + pp] + (float)(kk % 3) + (float)(pp - 1);
        float fy = floorf(py), fx = floorf(px);
        gy0[e] = (int)fy;
        gx0[e] = (int)fx;
        gwy[e] = py - fy;
        gwx[e] = px - fx;
    }
    __syncthreads();

    // ---------------- main loop: cols gather + GEMM ------------------------
    float* wlds = smem_big;              // [KCH][64co]
    float* cols = smem_big + KCH * 64;   // [KCH][64px]
    const int tx = t & 15;               // pixel group (4 px)
    const int ty = t >> 4;               // cout group (4 co)
    float accf[4][4] = {{0.f}};

    for (int c0 = 0; c0 < CIN; c0 += CCHUNK) {
        // stage weight chunk [KCH][64co]
        if (use_wt) {
            const float* wsrc = w_t + c0 * 9 * 64;
#pragma unroll
            for (int i = 0; i < 9; ++i) {
                int f = t + 256 * i;     // 2304 float2 = 4608 floats
                ((float2*)wlds)[f] = ((const float2*)wsrc)[f];
            }
        } else {
            const int co = t & 63;
#pragma unroll
            for (int i = 0; i < 18; ++i) {
                int kl = g * 18 + i;
                wlds[kl * 64 + co] = w_dcn[co * 576 + c0 * 9 + kl];
            }
        }
        // gather cols chunk [KCH][64px]; each thread: 18 values for pixel p
#pragma unroll
        for (int i = 0; i < 18; ++i) {
            int kl = g * 18 + i;               // 0..71
            int cinl = 2 * g + (i >= 9 ? 1 : 0);
            int kk = (i >= 9) ? (i - 9) : i;   // compile-time constant
            int e = kk * 64 + p;
            int y0 = gy0[e], x0 = gx0[e];
            float wy1 = gwy[e], wx1 = gwx[e];
            float wy0 = 1.f - wy1, wx0 = 1.f - wx1;
            const float* xc = xb + (size_t)(c0 + cinl) * (HDIM * WDIM);
            bool y0ok = ((unsigned)y0 < (unsigned)HDIM);
            bool y1ok = ((unsigned)(y0 + 1) < (unsigned)HDIM);
            bool x0ok = ((unsigned)x0 < (unsigned)WDIM);
            bool x1ok = ((unsigned)(x0 + 1) < (unsigned)WDIM);
            int base = y0 * WDIM + x0;
            float v00 = (y0ok && x0ok) ? xc[base] : 0.f;
            float v01 = (y0ok && x1ok) ? xc[base + 1] : 0.f;
            float v10 = (y1ok && x0ok) ? xc[base + WDIM] : 0.f;
            float v11 = (y1ok && x1ok) ? xc[base + WDIM + 1] : 0.f;
            cols[kl * 64 + p] =
                wy0 * (wx0 * v00 + wx1 * v01) + wy1 * (wx0 * v10 + wx1 * v11);
        }
        __syncthreads();

        // GEMM: 64co x 64px tile, thread tile 4co x 4px
#pragma unroll 8
        for (int k = 0; k < KCH; ++k) {
            float4 a4 = *(const float4*)&wlds[k * 64 + ty * 4];
            float4 b4 = *(const float4*)&cols[k * 64 + tx * 4];
            float av[4] = {a4.x, a4.y, a4.z, a4.w};
            float bv[4] = {b4.x, b4.y, b4.z, b4.w};
#pragma unroll
            for (int ii = 0; ii < 4; ++ii)
#pragma unroll
                for (int jj = 0; jj < 4; ++jj)
                    accf[ii][jj] += av[ii] * bv[jj];
        }
        __syncthreads();
    }

    // ---------------- epilogue: bias + store -------------------------------
#pragma unroll
    for (int i = 0; i < 4; ++i) {
        int co = ty * 4 + i;
        float bias = b_dcn[co];
        float4 v;
        v.x = accf[i][0] + bias;
        v.y = accf[i][1] + bias;
        v.z = accf[i][2] + bias;
        v.w = accf[i][3] + bias;
        *(float4*)&out[(((size_t)b * COUT + co) * HDIM + ho) * WDIM + tx * 4] = v;
    }
}

// ---------------------------------------------------------------------------
extern "C" void kernel_launch(void* const* d_in, const int* in_sizes, int n_in,
                              void* d_out, int out_size, void* d_ws, size_t ws_size,
                              hipStream_t stream) {
    const float* x     = (const float*)d_in[0];
    const float* w_off = (const float*)d_in[1];
    const float* b_off = (const float*)d_in[2];
    const float* w_dcn = (const float*)d_in[3];
    const float* b_dcn = (const float*)d_in[4];
    float* out = (float*)d_out;
    float* w_t = (float*)d_ws;

    int use_wt = (ws_size >= 576 * 64 * sizeof(float)) ? 1 : 0;
    if (use_wt) {
        transpose_w<<<144, 256, 0, stream>>>(w_dcn, w_t);
    }
    dcn_main<<<1024, 256, 0, stream>>>(x, w_off, b_off, w_dcn, w_t, b_dcn, out,
                                       use_wt);
}

// Round 2
// 273.153 us; speedup vs baseline: 1.0857x; 1.0857x over previous
//
#include <hip/hip_runtime.h>
#include <hip/hip_fp16.h>

// DeformConv2d: B=16, Cin=64, Cout=64, H=W=64, K=3, stride=1, pad=1, dil=1
// Round 2: f16 MFMA main GEMM (18 k-groups of 32), LDS diet -> 5 blocks/CU.

#define KOFF 18
#define CIN 64
#define COUT 64
#define HDIM 64
#define WDIM 64
#define CPAD 40          // padded k-stride (halfs) for colsT/wlds: 80B rows, 2-way banks
#define GSTR 66          // geom tap stride (uint2) to spread banks, keeps 16B align

typedef _Float16 half8 __attribute__((ext_vector_type(8)));
typedef float floatx4 __attribute__((ext_vector_type(4)));

// ---------------------------------------------------------------------------
// convert w_dcn [64co][576k] fp32 -> f16 (same layout) in ws
__global__ void cvt_w(const float* __restrict__ w_dcn, _Float16* __restrict__ w2) {
    int e = blockIdx.x * 256 + threadIdx.x;
    if (e < 576 * 64) w2[e] = (_Float16)w_dcn[e];
}

// ---------------------------------------------------------------------------
__launch_bounds__(256)
__global__ void dcn_main(const float* __restrict__ x,
                         const float* __restrict__ w_off,
                         const float* __restrict__ b_off,
                         const float* __restrict__ w_dcn,
                         const _Float16* __restrict__ w2,
                         const float* __restrict__ b_dcn,
                         float* __restrict__ out,
                         int use_wt) {
    const int bx = blockIdx.x;       // 0..1023
    const int b  = bx >> 6;
    const int ho = bx & 63;
    const int t  = threadIdx.x;
    const int p  = t & 63;
    const int g  = t >> 6;           // wave id

    __shared__ float offlds[KOFF * 64];              // 4608 B
    __shared__ uint2 geom[9 * GSTR];                 // 4752 B
    __shared__ __align__(16) char dynbuf[18432];     // partial | colsT+wlds
    float*    partial = (float*)dynbuf;              // 4*18*64 floats
    _Float16* colsT   = (_Float16*)dynbuf;           // [64px][CPAD]
    _Float16* wlds    = (_Float16*)(dynbuf + 64 * CPAD * 2); // [64co][CPAD]

    const float* xb = x + (size_t)b * CIN * HDIM * WDIM;

    // ---------------- phase -1: offset conv (VALU, 4-way cin split) --------
    {
        const int cinbase = __builtin_amdgcn_readfirstlane(g * 16);
        const float* wbase = w_off + cinbase * 9;
        float acc[KOFF];
#pragma unroll
        for (int i = 0; i < KOFF; ++i) acc[i] = 0.f;

        for (int ci = 0; ci < 16; ++ci) {
            const float* xc = xb + (size_t)(cinbase + ci) * (HDIM * WDIM);
#pragma unroll
            for (int ky = 0; ky < 3; ++ky) {
                int y = ho + ky - 1;
                bool yok = ((unsigned)y < (unsigned)HDIM);
#pragma unroll
                for (int kx = 0; kx < 3; ++kx) {
                    int xcol = p + kx - 1;
                    bool ok = yok && ((unsigned)xcol < (unsigned)WDIM);
                    float xv = ok ? xc[y * WDIM + xcol] : 0.f;
#pragma unroll
                    for (int co = 0; co < KOFF; ++co)
                        acc[co] += xv * wbase[co * 576 + ci * 9 + ky * 3 + kx];
                }
            }
        }
#pragma unroll
        for (int co = 0; co < KOFF; ++co)
            partial[(g * KOFF + co) * 64 + p] = acc[co];
        __syncthreads();
        for (int e = t; e < KOFF * 64; e += 256) {
            int co = e >> 6, pp = e & 63;
            float s = b_off[co];
#pragma unroll
            for (int q = 0; q < 4; ++q) s += partial[(q * KOFF + co) * 64 + pp];
            offlds[e] = s;
        }
        __syncthreads();
    }

    // ---------------- phase 0: packed bilinear geometry --------------------
    for (int e = t; e < 9 * 64; e += 256) {
        int kk = e >> 6, pp = e & 63;
        float py  = offlds[(2 * kk) * 64 + pp] + (float)(kk / 3) + (float)(ho - 1);
        float pxx = offlds[(2 * kk + 1) * 64 + pp] + (float)(kk % 3) + (float)(pp - 1);
        float fy = floorf(py), fx = floorf(pxx);
        int y0 = (int)fy, x0 = (int)fx;
        union { __half2 h; unsigned u; } cv;
        cv.h = __floats2half2_rn(py - fy, pxx - fx);   // .x = wy1, .y = wx1
        uint2 gv;
        gv.x = ((unsigned)(y0 & 0xffff)) | ((unsigned)x0 << 16);
        gv.y = cv.u;
        geom[kk * GSTR + pp] = gv;
    }
    __syncthreads();

    // ---------------- main loop: 18 k-groups of 32 -------------------------
    const int lane = t & 63;
    const int kl   = t & 31;            // k within group (gather role)
    const int px0  = (t >> 5) * 8;      // 8-pixel strip (gather role)
    const int wco  = t >> 2;            // staging role: cout
    const int wkoff = (t & 3) * 8;      // staging role: k offset
    floatx4 acc[4];
#pragma unroll
    for (int nt = 0; nt < 4; ++nt) acc[nt] = (floatx4){0.f, 0.f, 0.f, 0.f};

    for (int kg0 = 0; kg0 < 576; kg0 += 32) {
        // ---- stage weight k-group [64co][32k] -> wlds ----
        if (use_wt) {
            half8 wv = *(const half8*)&w2[wco * 576 + kg0 + wkoff];
            *(half8*)&wlds[wco * CPAD + wkoff] = wv;
        } else {
            const float4* ws4 = (const float4*)&w_dcn[wco * 576 + kg0 + wkoff];
            float4 f0 = ws4[0], f1 = ws4[1];
            half8 wv;
            wv[0] = (_Float16)f0.x; wv[1] = (_Float16)f0.y;
            wv[2] = (_Float16)f0.z; wv[3] = (_Float16)f0.w;
            wv[4] = (_Float16)f1.x; wv[5] = (_Float16)f1.y;
            wv[6] = (_Float16)f1.z; wv[7] = (_Float16)f1.w;
            *(half8*)&wlds[wco * CPAD + wkoff] = wv;
        }

        // ---- gather: this thread owns k = kg0+kl, pixels px0..px0+7 ----
        int kg  = kg0 + kl;
        int cin = kg / 9;
        int tap = kg - cin * 9;
        const float* xc = xb + (size_t)cin * (HDIM * WDIM);
        uint2 gq[8];
        const uint4* gp = (const uint4*)&geom[tap * GSTR + px0];
#pragma unroll
        for (int i2 = 0; i2 < 4; ++i2) ((uint4*)gq)[i2] = gp[i2];
#pragma unroll
        for (int i = 0; i < 8; ++i) {
            int y0 = (int)(short)(gq[i].x & 0xffffu);
            int x0 = (int)(short)(gq[i].x >> 16);
            union { unsigned u; __half2 h; } cv; cv.u = gq[i].y;
            float wy1 = __half2float(cv.h.x);
            float wx1 = __half2float(cv.h.y);
            float wy0 = 1.f - wy1, wx0 = 1.f - wx1;
            bool y0ok = ((unsigned)y0 < (unsigned)HDIM);
            bool y1ok = ((unsigned)(y0 + 1) < (unsigned)HDIM);
            bool x0ok = ((unsigned)x0 < (unsigned)WDIM);
            bool x1ok = ((unsigned)(x0 + 1) < (unsigned)WDIM);
            int base = y0 * WDIM + x0;
            float v00 = (y0ok && x0ok) ? xc[base] : 0.f;
            float v01 = (y0ok && x1ok) ? xc[base + 1] : 0.f;
            float v10 = (y1ok && x0ok) ? xc[base + WDIM] : 0.f;
            float v11 = (y1ok && x1ok) ? xc[base + WDIM + 1] : 0.f;
            float v = wy0 * (wx0 * v00 + wx1 * v01) + wy1 * (wx0 * v10 + wx1 * v11);
            colsT[(px0 + i) * CPAD + kl] = (_Float16)v;
        }
        __syncthreads();

        // ---- MFMA: wave g -> cout rows [16g,16g+16), 4 px tiles ----
        half8 afrag = *(const half8*)&wlds[(g * 16 + (lane & 15)) * CPAD + (lane >> 4) * 8];
#pragma unroll
        for (int nt = 0; nt < 4; ++nt) {
            half8 bfrag = *(const half8*)&colsT[(nt * 16 + (lane & 15)) * CPAD + (lane >> 4) * 8];
            acc[nt] = __builtin_amdgcn_mfma_f32_16x16x32_f16(afrag, bfrag, acc[nt], 0, 0, 0);
        }
        __syncthreads();
    }

    // ---------------- epilogue: bias + store -------------------------------
    const int col   = lane & 15;
    const int rbase = (lane >> 4) * 4;
    float bias[4];
#pragma unroll
    for (int r = 0; r < 4; ++r) bias[r] = b_dcn[g * 16 + rbase + r];
#pragma unroll
    for (int nt = 0; nt < 4; ++nt) {
        int wo = nt * 16 + col;
#pragma unroll
        for (int r = 0; r < 4; ++r) {
            int co = g * 16 + rbase + r;
            out[(((size_t)b * COUT + co) * HDIM + ho) * WDIM + wo] = acc[nt][r] + bias[r];
        }
    }
}

// ---------------------------------------------------------------------------
extern "C" void kernel_launch(void* const* d_in, const int* in_sizes, int n_in,
                              void* d_out, int out_size, void* d_ws, size_t ws_size,
                              hipStream_t stream) {
    const float* x     = (const float*)d_in[0];
    const float* w_off = (const float*)d_in[1];
    const float* b_off = (const float*)d_in[2];
    const float* w_dcn = (const float*)d_in[3];
    const float* b_dcn = (const float*)d_in[4];
    float* out = (float*)d_out;
    _Float16* w2 = (_Float16*)d_ws;

    int use_wt = (ws_size >= 576 * 64 * sizeof(_Float16)) ? 1 : 0;
    if (use_wt) {
        cvt_w<<<144, 256, 0, stream>>>(w_dcn, w2);
    }
    dcn_main<<<1024, 256, 0, stream>>>(x, w_off, b_off, w_dcn, w2, b_dcn, out,
                                       use_wt);
}